// Round 5
// baseline (269.607 us; speedup 1.0000x reference)
//
#include <hip/hip_runtime.h>
#include <math.h>

#define DEV __device__ __forceinline__

constexpr int N_TRAIN = 131072;
constexpr int M_TEST  = 65536;
constexpr int T_TOT   = N_TRAIN + M_TEST;  // 196608
constexpr int CHUNK   = 3;
constexpr int TPB     = 256;
constexpr int NTH     = T_TOT / CHUNK;     // 65536 threads
constexpr int NBLK    = NTH / TPB;         // 256 blocks
constexpr int FE_S    = 27;                // packed FE stride (doubles)
constexpr int SE_S    = 19;                // SE LDS stride (18 packed + 1 pad)

// ---------------- software grid barrier ----------------
// Safe: 256 blocks, __launch_bounds__(256,2) => VGPR<=256, LDS 55KB => at least
// 1 block/CU guaranteed resident on all 256 CUs (2x slack), so all blocks spin
// concurrently. Counters are zeroed by k_init each launch (ws is re-poisoned).
DEV void grid_barrier(unsigned* cnt, int slot) {
  __syncthreads();
  if (threadIdx.x == 0) {
    __threadfence();   // release all prior writes to device scope
    __hip_atomic_fetch_add(&cnt[slot], 1u, __ATOMIC_ACQ_REL, __HIP_MEMORY_SCOPE_AGENT);
    while (__hip_atomic_load(&cnt[slot], __ATOMIC_ACQUIRE, __HIP_MEMORY_SCOPE_AGENT) < (unsigned)NBLK) {
      __builtin_amdgcn_s_sleep(8);
    }
    __threadfence();   // acquire
  }
  __syncthreads();
}

__global__ void k_init(unsigned* cnt) {
  if (threadIdx.x < 8) cnt[threadIdx.x] = 0u;
}

// ---------------- 3x3 helpers (row-major double[9]) ----------------
DEV void mm(const double* X, const double* Y, double* Z) {
#pragma unroll
  for (int i = 0; i < 3; ++i)
#pragma unroll
    for (int j = 0; j < 3; ++j)
      Z[i*3+j] = X[i*3]*Y[j] + X[i*3+1]*Y[3+j] + X[i*3+2]*Y[6+j];
}
DEV void mmnt(const double* X, const double* Y, double* Z) { // X * Y^T
#pragma unroll
  for (int i = 0; i < 3; ++i)
#pragma unroll
    for (int j = 0; j < 3; ++j)
      Z[i*3+j] = X[i*3]*Y[j*3] + X[i*3+1]*Y[j*3+1] + X[i*3+2]*Y[j*3+2];
}
DEV void mtn(const double* X, const double* Y, double* Z) { // X^T * Y
#pragma unroll
  for (int i = 0; i < 3; ++i)
#pragma unroll
    for (int j = 0; j < 3; ++j)
      Z[i*3+j] = X[i]*Y[j] + X[3+i]*Y[3+j] + X[6+i]*Y[6+j];
}
DEV void mv(const double* X, const double* v, double* w) {
#pragma unroll
  for (int i = 0; i < 3; ++i) w[i] = X[i*3]*v[0] + X[i*3+1]*v[1] + X[i*3+2]*v[2];
}
DEV void mtv(const double* X, const double* v, double* w) {
#pragma unroll
  for (int i = 0; i < 3; ++i) w[i] = X[i]*v[0] + X[3+i]*v[1] + X[6+i]*v[2];
}
DEV void inv3(const double* m, double* o) {
  double c00 = m[4]*m[8] - m[5]*m[7];
  double c10 = m[5]*m[6] - m[3]*m[8];
  double c20 = m[3]*m[7] - m[4]*m[6];
  double det = m[0]*c00 + m[1]*c10 + m[2]*c20;
  double id = 1.0 / det;
  o[0] = c00*id; o[1] = (m[2]*m[7]-m[1]*m[8])*id; o[2] = (m[1]*m[5]-m[2]*m[4])*id;
  o[3] = c10*id; o[4] = (m[0]*m[8]-m[2]*m[6])*id; o[5] = (m[2]*m[3]-m[0]*m[5])*id;
  o[6] = c20*id; o[7] = (m[1]*m[6]-m[0]*m[7])*id; o[8] = (m[0]*m[4]-m[1]*m[3])*id;
}
DEV void symm(double* P) {
  double a = 0.5*(P[1]+P[3]), b = 0.5*(P[2]+P[6]), c = 0.5*(P[5]+P[7]);
  P[1]=P[3]=a; P[2]=P[6]=b; P[5]=P[7]=c;
}

// ---------------- model ----------------
struct Model { double lam, v, kap, l4; };
DEV Model make_model(const float* varp, const float* ellp) {
  Model M; M.v = (double)varp[0];
  double ell = (double)ellp[0];
  M.lam = sqrt(5.0) / ell;
  M.kap = M.lam * M.lam / 3.0;
  double l2 = M.lam * M.lam;
  M.l4 = l2 * l2;
  return M;
}
DEV void pinf(const Model& M, double* P) {
  double vk = M.v * M.kap;
  P[0]=M.v; P[1]=0;  P[2]=-vk;
  P[3]=0;   P[4]=vk; P[5]=0;
  P[6]=-vk; P[7]=0;  P[8]=M.v*M.l4;
}
// A = exp(dt*F) = e^{-lam dt}(I + dt*N + dt^2/2 N^2); Q = Pinf - A Pinf A^T
// exp via fp32 HW (lam*dt small here; rel err ~1e-7, below fp32-ref noise)
DEV void make_AQ(const Model& M, double dt, double* A, double* Q) {
  double lam = M.lam, l2 = lam*lam, l3 = l2*lam, l4 = M.l4;
  double e = (double)__expf((float)(-lam * dt));
  double h = 0.5 * dt * dt;
  A[0] = e*(1.0 + dt*lam + h*l2);
  A[1] = e*(dt + 2.0*h*lam);
  A[2] = e*h;
  A[3] = e*(-h*l3);
  A[4] = e*(1.0 + dt*lam - 2.0*h*l2);
  A[5] = e*(dt - h*lam);
  A[6] = e*(-dt*l3 + h*l4);
  A[7] = e*(-3.0*dt*l2 + 2.0*h*l3);
  A[8] = e*(1.0 - 2.0*dt*lam + h*l2);
  double vk = M.v * M.kap, vl4 = M.v * M.l4;
  double B[9];  // A * Pinf
#pragma unroll
  for (int i = 0; i < 3; ++i) {
    B[i*3+0] =  A[i*3+0]*M.v - A[i*3+2]*vk;
    B[i*3+1] =  A[i*3+1]*vk;
    B[i*3+2] = -A[i*3+0]*vk  + A[i*3+2]*vl4;
  }
  double Pi[9]; pinf(M, Pi);
#pragma unroll
  for (int i = 0; i < 3; ++i)
#pragma unroll
    for (int j = 0; j < 3; ++j)
      Q[i*3+j] = Pi[i*3+j] - (B[i*3]*A[j*3] + B[i*3+1]*A[j*3+1] + B[i*3+2]*A[j*3+2]);
}

// ---------------- filter scan element ----------------
struct FE { double A[9]; double b[3]; double C[9]; double h[3]; double J[9]; };

DEV FE fe_identity() {
  FE e;
#pragma unroll
  for (int i=0;i<9;++i){ e.A[i]=0.0; e.C[i]=0.0; e.J[i]=0.0; }
  e.A[0]=e.A[4]=e.A[8]=1.0;
  e.b[0]=e.b[1]=e.b[2]=0.0; e.h[0]=e.h[1]=e.h[2]=0.0;
  return e;
}
// packed-27: A[0..8] b[9..11] Csym[12..17] h[18..20] Jsym[21..26]
DEV void fe_pack27(const FE& e, double* g) {
#pragma unroll
  for (int i=0;i<9;++i) g[i]=e.A[i];
  g[9]=e.b[0]; g[10]=e.b[1]; g[11]=e.b[2];
  g[12]=e.C[0]; g[13]=e.C[1]; g[14]=e.C[2]; g[15]=e.C[4]; g[16]=e.C[5]; g[17]=e.C[8];
  g[18]=e.h[0]; g[19]=e.h[1]; g[20]=e.h[2];
  g[21]=e.J[0]; g[22]=e.J[1]; g[23]=e.J[2]; g[24]=e.J[4]; g[25]=e.J[5]; g[26]=e.J[8];
}
DEV FE fe_unpack27(const double* g) {
  FE e;
#pragma unroll
  for (int i=0;i<9;++i) e.A[i]=g[i];
  e.b[0]=g[9]; e.b[1]=g[10]; e.b[2]=g[11];
  e.C[0]=g[12]; e.C[1]=g[13]; e.C[2]=g[14]; e.C[3]=g[13]; e.C[4]=g[15];
  e.C[5]=g[16]; e.C[6]=g[14]; e.C[7]=g[16]; e.C[8]=g[17];
  e.h[0]=g[18]; e.h[1]=g[19]; e.h[2]=g[20];
  e.J[0]=g[21]; e.J[1]=g[22]; e.J[2]=g[23]; e.J[3]=g[22]; e.J[4]=g[24];
  e.J[5]=g[25]; e.J[6]=g[23]; e.J[7]=g[25]; e.J[8]=g[26];
  return e;
}
DEV FE build_felem(const Model& M, double dt, float obsf, float rf, float Rf_, bool first) {
  FE E;
  double r = (double)rf, R = (double)Rf_;
  double g = (obsf > 0.5f) ? 1.0 : 0.0;
  if (first) {
#pragma unroll
    for (int i=0;i<9;++i){ E.A[i]=0.0; E.J[i]=0.0; }
    E.h[0]=E.h[1]=E.h[2]=0.0;
    double Pi[9]; pinf(M, Pi);
    double S = Pi[0] + R;
    double f = g / S;
    double K0=Pi[0]*f, K1=Pi[3]*f, K2=Pi[6]*f;
    E.b[0]=K0*r; E.b[1]=K1*r; E.b[2]=K2*r;
    E.C[0]=Pi[0]-S*K0*K0; E.C[1]=Pi[1]-S*K0*K1; E.C[2]=Pi[2]-S*K0*K2;
    E.C[3]=Pi[3]-S*K1*K0; E.C[4]=Pi[4]-S*K1*K1; E.C[5]=Pi[5]-S*K1*K2;
    E.C[6]=Pi[6]-S*K2*K0; E.C[7]=Pi[7]-S*K2*K1; E.C[8]=Pi[8]-S*K2*K2;
    return E;
  }
  double Am[9], Q[9]; make_AQ(M, dt, Am, Q);
  double S = Q[0] + R, iS = g / S;   // gated: obs=0 -> K=0, A=Am, C=Q, h=0, J=0
  double K0=Q[0]*iS, K1=Q[3]*iS, K2=Q[6]*iS;
#pragma unroll
  for (int j = 0; j < 3; ++j) {
    E.A[j]   = Am[j]   - K0*Am[j];
    E.A[3+j] = Am[3+j] - K1*Am[j];
    E.A[6+j] = Am[6+j] - K2*Am[j];
    E.C[j]   = Q[j]    - K0*Q[j];
    E.C[3+j] = Q[3+j]  - K1*Q[j];
    E.C[6+j] = Q[6+j]  - K2*Q[j];
  }
  E.b[0]=K0*r; E.b[1]=K1*r; E.b[2]=K2*r;
  double riS = r*iS;
  E.h[0]=Am[0]*riS; E.h[1]=Am[1]*riS; E.h[2]=Am[2]*riS;
#pragma unroll
  for (int i = 0; i < 3; ++i)
#pragma unroll
    for (int j = 0; j < 3; ++j)
      E.J[i*3+j] = Am[i]*Am[j]*iS;
  return E;
}
// compose: x earlier, y later
DEV FE fcompose(const FE& x, const FE& y) {
  const double *A1=x.A,*b1=x.b,*C1=x.C,*h1=x.h,*J1=x.J;
  const double *A2=y.A,*b2=y.b,*C2=y.C,*h2=y.h,*J2=y.J;
  FE o;
  double Mx[9]; mm(C1,J2,Mx); Mx[0]+=1.0; Mx[4]+=1.0; Mx[8]+=1.0;
  double Mi[9]; inv3(Mx,Mi);
  double T1[9]; mm(A2,Mi,T1);
  mm(T1,A1,o.A);
  double u[3]; mv(C1,h2,u); u[0]+=b1[0]; u[1]+=b1[1]; u[2]+=b1[2];
  mv(T1,u,o.b); o.b[0]+=b2[0]; o.b[1]+=b2[1]; o.b[2]+=b2[2];
  double t2[9]; mm(T1,C1,t2);
  mmnt(t2,A2,o.C);
#pragma unroll
  for (int i=0;i<9;++i) o.C[i]+=C2[i];
  double tmp[9]; mm(Mi,A1,tmp);
  double w[3]; mv(J2,b1,w);
  w[0]=h2[0]-w[0]; w[1]=h2[1]-w[1]; w[2]=h2[2]-w[2];
  mtv(tmp,w,o.h); o.h[0]+=h1[0]; o.h[1]+=h1[1]; o.h[2]+=h1[2];
  double V[9]; mm(J2,A1,V);
  mtn(tmp,V,o.J);
#pragma unroll
  for (int i=0;i<9;++i) o.J[i]+=J1[i];
  symm(o.C); symm(o.J);
  return o;
}
// plain Kalman step (replay)
DEV void fstep(const Model& M, double dt, float obsf, float rf, float Rf_,
               double* m, double* P) {
  double A[9], Q[9]; make_AQ(M, dt, A, Q);
  double mp[3]; mv(A, m, mp);
  double W[9]; mmnt(P, A, W);      // P A^T
  double Pp[9]; mm(A, W, Pp);
#pragma unroll
  for (int i=0;i<9;++i) Pp[i]+=Q[i];
  double S = Pp[0] + (double)Rf_;
  double f = (obsf > 0.5f) ? (1.0/S) : 0.0;
  double K0=Pp[0]*f, K1=Pp[3]*f, K2=Pp[6]*f;
  double v = (double)rf - mp[0];
  m[0]=mp[0]+K0*v; m[1]=mp[1]+K1*v; m[2]=mp[2]+K2*v;
  P[0]=Pp[0]-S*K0*K0; P[1]=Pp[1]-S*K0*K1; P[2]=Pp[2]-S*K0*K2;
  P[3]=Pp[3]-S*K1*K0; P[4]=Pp[4]-S*K1*K1; P[5]=Pp[5]-S*K1*K2;
  P[6]=Pp[6]-S*K2*K0; P[7]=Pp[7]-S*K2*K1; P[8]=Pp[8]-S*K2*K2;
  symm(P);
}

// ---------------- smoother affine map: x_k = G x_{k+1} + c ; P_k = G P G^T + U ----------------
struct SE { double G[9]; double c[3]; double U[9]; };

DEV void se_store(const SE& s, double* g) {   // packed-18
#pragma unroll
  for (int i=0;i<9;++i) g[i]=s.G[i];
  g[9]=s.c[0]; g[10]=s.c[1]; g[11]=s.c[2];
  g[12]=s.U[0]; g[13]=s.U[1]; g[14]=s.U[2]; g[15]=s.U[4]; g[16]=s.U[5]; g[17]=s.U[8];
}
DEV SE se_load(const double* g) {
  SE s;
#pragma unroll
  for (int i=0;i<9;++i) s.G[i]=g[i];
  s.c[0]=g[9]; s.c[1]=g[10]; s.c[2]=g[11];
  s.U[0]=g[12]; s.U[1]=g[13]; s.U[2]=g[14];
  s.U[3]=g[13]; s.U[4]=g[15]; s.U[5]=g[16];
  s.U[6]=g[14]; s.U[7]=g[16]; s.U[8]=g[17];
  return s;
}
// x earlier in time (applied LAST, since smoother runs backward)
DEV SE scompose(const SE& x, const SE& y) {
  SE o;
  mm(x.G, y.G, o.G);
  double t[3]; mv(x.G, y.c, t);
  o.c[0]=t[0]+x.c[0]; o.c[1]=t[1]+x.c[1]; o.c[2]=t[2]+x.c[2];
  double T[9]; mm(x.G, y.U, T);
  mmnt(T, x.G, o.U);
#pragma unroll
  for (int i=0;i<9;++i) o.U[i]+=x.U[i];
  symm(o.U);
  return o;
}
DEV void sapply(const SE& s, double* m, double* P) {
  double t[3]; mv(s.G, m, t);
  double T[9]; mm(s.G, P, T);
  double Pn[9]; mmnt(T, s.G, Pn);
  m[0]=t[0]+s.c[0]; m[1]=t[1]+s.c[1]; m[2]=t[2]+s.c[2];
#pragma unroll
  for (int i=0;i<9;++i) P[i]=Pn[i]+s.U[i];
  symm(P);
}
// SE from filtered state (m,P) at k and dt to k+1 (no memory traffic)
DEV SE selem_from_state(const Model& M, const double* m, const double* P, double dt) {
  SE s;
  double A[9], Q[9]; make_AQ(M, dt, A, Q);
  double W[9]; mmnt(P, A, W);      // P A^T
  double Pp[9]; mm(A, W, Pp);
#pragma unroll
  for (int j=0;j<9;++j) Pp[j]+=Q[j];
  double Pi_[9]; inv3(Pp, Pi_);
  mm(W, Pi_, s.G);                 // G = P A^T Pp^-1
  double mp[3]; mv(A, m, mp);
  double gm[3]; mv(s.G, mp, gm);
  s.c[0]=m[0]-gm[0]; s.c[1]=m[1]-gm[1]; s.c[2]=m[2]-gm[2];
  double GW[9]; mmnt(s.G, W, GW);  // G Pp G^T
#pragma unroll
  for (int j=0;j<9;++j) s.U[j]=P[j]-GW[j];
  symm(s.U);
  return s;
}
// SE rebuilt from stored mf/Pf (replay phase G)
DEV SE build_selem(const Model& M, const float4* pk, const double* mf, const double* Pf,
                   int i, int t) {
  int ik  = i*NTH + t;
  int ik1 = (i < CHUNK-1) ? (ik + NTH) : (t + 1);
  double m[3] = { mf[ik], mf[T_TOT+ik], mf[2*T_TOT+ik] };
  double p00=Pf[ik], p01=Pf[T_TOT+ik], p02=Pf[2*T_TOT+ik],
         p11=Pf[3*T_TOT+ik], p12=Pf[4*T_TOT+ik], p22=Pf[5*T_TOT+ik];
  double P[9] = { p00,p01,p02, p01,p11,p12, p02,p12,p22 };
  double dt = (double)(pk[ik1].x - pk[ik].x);
  return selem_from_state(M, m, P, dt);
}

// ================= the single fused kernel (software grid barriers) =================
struct KP {
  const float *times, *tstar, *n1, *n2, *varp, *ellp, *mcp;
  float4* pk; int* oix;
  double *mf, *Pf, *blkAgg, *blkPref, *blkAggS, *bExit, *xT;
  unsigned* cnt;
  float* out;
};

__global__ __launch_bounds__(TPB, 2) void k_all(KP p) {
  __shared__ double lds[TPB * FE_S];   // 55,296 B; FE scan stride 27, SE scan stride 19
  const int l = threadIdx.x, b = blockIdx.x;
  const int t = b * TPB + l;
  const Model M = make_model(p.varp, p.ellp);

  // ---------- phase A: merge (3 items per thread, coalesced) ----------
  {
    float mc = p.mcp[0];
#pragma unroll
    for (int i = 0; i < CHUNK; ++i) {
      int g = i * NTH + t;
      if (g < N_TRAIN) {
        float tv = p.times[g];
        int lo = 0, hi = M_TEST;                 // count tstar strictly < tv
        while (lo < hi) { int mid=(lo+hi)>>1; if (p.tstar[mid] < tv) lo=mid+1; else hi=mid; }
        int pos = g + lo, ip = (pos % 3) * NTH + pos / 3;
        float s2 = p.n2[g];
        p.pk[ip] = make_float4(tv, p.n1[g]/s2 - mc, 1.0f/s2, 1.0f);
        p.oix[ip] = -1;
      } else {
        int j = g - N_TRAIN;
        float tv = p.tstar[j];
        int lo = 0, hi = N_TRAIN;                // count times <= tv (stable: train first)
        while (lo < hi) { int mid=(lo+hi)>>1; if (p.times[mid] <= tv) lo=mid+1; else hi=mid; }
        int pos = j + lo, ip = (pos % 3) * NTH + pos / 3;
        p.pk[ip] = make_float4(tv, 0.f, 1.f, 0.f);
        p.oix[ip] = j;
      }
    }
  }
  grid_barrier(p.cnt, 0);

  // ---------- phase B: filter chunk build + in-block inclusive scan ----------
  FE run;
  {
    float tprev = (t == 0) ? 0.0f : p.pk[(CHUNK-1)*NTH + (t-1)].x;
#pragma unroll
    for (int i = 0; i < CHUNK; ++i) {
      float4 q = p.pk[i*NTH + t];
      bool first = (t==0 && i==0);
      double dt = first ? 0.0 : (double)(q.x - tprev);
      tprev = q.x;
      FE e = build_felem(M, dt, q.w, q.y, q.z, first);
      run = (i == 0) ? e : fcompose(run, e);
    }
    fe_pack27(run, &lds[l*FE_S]);
    for (int d = 1; d < TPB; d <<= 1) {
      __syncthreads();
      FE oth; bool act = (l >= d);
      if (act) oth = fe_unpack27(&lds[(l-d)*FE_S]);
      __syncthreads();
      if (act) { run = fcompose(oth, run); fe_pack27(run, &lds[l*FE_S]); }
    }
    __syncthreads();
    if (l == TPB-1) fe_pack27(run, p.blkAgg + b*FE_S);
  }
  // block 0's LDS will be clobbered in phase C -> keep its exclusive prefix in regs
  FE entpre0;
  if (b == 0 && l > 0) entpre0 = fe_unpack27(&lds[(l-1)*FE_S]);
  grid_barrier(p.cnt, 1);

  // ---------- phase C: block 0 scans the 256 block aggregates ----------
  if (b == 0) {
    FE mine = fe_unpack27(p.blkAgg + l*FE_S);
    fe_pack27(mine, &lds[l*FE_S]);
    for (int d = 1; d < TPB; d <<= 1) {
      __syncthreads();
      FE oth; bool act = (l >= d);
      if (act) oth = fe_unpack27(&lds[(l-d)*FE_S]);
      __syncthreads();
      if (act) { mine = fcompose(oth, mine); fe_pack27(mine, &lds[l*FE_S]); }
    }
    __syncthreads();
    if (l == 0) { FE id = fe_identity(); fe_pack27(id, p.blkPref); }
    else {
#pragma unroll
      for (int i = 0; i < FE_S; ++i) p.blkPref[l*FE_S + i] = lds[(l-1)*FE_S + i];
    }
  }
  grid_barrier(p.cnt, 2);

  // ---------- phase D: filter replay + fused smoother element build + SE scan ----------
  SE runse;
  {
    double m[3], P[9];
    if (t == 0) {
      m[0]=m[1]=m[2]=0.0; pinf(M, P);
    } else {
      FE bp = fe_unpack27(p.blkPref + b*FE_S);
      FE ent;
      if (l == 0) ent = bp;
      else if (b == 0) ent = fcompose(bp, entpre0);
      else ent = fcompose(bp, fe_unpack27(&lds[(l-1)*FE_S]));   // LDS intact for b!=0
      m[0]=ent.b[0]; m[1]=ent.b[1]; m[2]=ent.b[2];
#pragma unroll
      for (int i=0;i<9;++i) P[i]=ent.C[i];
    }
    float tprev = (t == 0) ? 0.0f : p.pk[(CHUNK-1)*NTH + (t-1)].x;
    bool haveSe = false;
#pragma unroll
    for (int i = 0; i < CHUNK; ++i) {
      int ik = i*NTH + t;
      float4 q = p.pk[ik];
      bool first = (t==0 && i==0);
      double dt = first ? 0.0 : (double)(q.x - tprev);
      tprev = q.x;
      fstep(M, dt, q.w, q.y, q.z, m, P);
      p.mf[ik]=m[0]; p.mf[T_TOT+ik]=m[1]; p.mf[2*T_TOT+ik]=m[2];
      p.Pf[ik]=P[0]; p.Pf[T_TOT+ik]=P[1]; p.Pf[2*T_TOT+ik]=P[2];
      p.Pf[3*T_TOT+ik]=P[4]; p.Pf[4*T_TOT+ik]=P[5]; p.Pf[5*T_TOT+ik]=P[8];
      int k = CHUNK*t + i;
      if (k <= T_TOT-2) {   // smoother element from register state
        int ik1 = (i < CHUNK-1) ? (ik + NTH) : (t + 1);
        double dtn = (double)(p.pk[ik1].x - q.x);
        SE e = selem_from_state(M, m, P, dtn);
        runse = haveSe ? scompose(runse, e) : e;
        haveSe = true;
      }
    }
    if (t == NTH-1) {  // final filtered state (= final smoothed)
      p.xT[0]=m[0]; p.xT[1]=m[1]; p.xT[2]=m[2];
      p.xT[3]=P[0]; p.xT[4]=P[1]; p.xT[5]=P[2];
      p.xT[6]=P[4]; p.xT[7]=P[5]; p.xT[8]=P[8];
    }
  }
  // in-block backward (suffix) scan of SE
  __syncthreads();   // everyone done reading FE data from LDS
  se_store(runse, &lds[l*SE_S]);
  for (int d = 1; d < TPB; d <<= 1) {
    __syncthreads();
    SE oth; bool act = (l + d < TPB);
    if (act) oth = se_load(&lds[(l+d)*SE_S]);
    __syncthreads();
    if (act) { runse = scompose(runse, oth); se_store(runse, &lds[l*SE_S]); }
  }
  __syncthreads();
  // block 0's LDS will be clobbered in phase F -> keep its next-suffix in regs
  SE sufnext0;
  if (b == 0 && l < TPB-1) sufnext0 = se_load(&lds[(l+1)*SE_S]);
  if (l == 0) se_store(runse, p.blkAggS + b*18);
  grid_barrier(p.cnt, 3);

  // ---------- phase F: block 0 backward-scans block aggregates -> bExit ----------
  if (b == 0) {
    SE mine = se_load(p.blkAggS + l*18);
    __syncthreads();
    se_store(mine, &lds[l*SE_S]);
    for (int d = 1; d < TPB; d <<= 1) {
      __syncthreads();
      SE oth; bool act = (l + d < TPB);
      if (act) oth = se_load(&lds[(l+d)*SE_S]);
      __syncthreads();
      if (act) { mine = scompose(mine, oth); se_store(mine, &lds[l*SE_S]); }
    }
    __syncthreads();
    double m[3] = { p.xT[0], p.xT[1], p.xT[2] };
    double P[9] = { p.xT[3],p.xT[4],p.xT[5], p.xT[4],p.xT[6],p.xT[7], p.xT[5],p.xT[7],p.xT[8] };
    if (l < TPB-1) {
      SE s = se_load(&lds[(l+1)*SE_S]);   // suffix of blocks l+1..255
      sapply(s, m, P);
    }
    double* o = p.bExit + l*9;
    o[0]=m[0];o[1]=m[1];o[2]=m[2];o[3]=P[0];o[4]=P[1];o[5]=P[2];o[6]=P[4];o[7]=P[5];o[8]=P[8];
  }
  grid_barrier(p.cnt, 4);

  // ---------- phase G: smoother replay + outputs ----------
  {
    double mc = (double)p.mcp[0];
    const double* g = p.bExit + b*9;
    double m[3] = { g[0], g[1], g[2] };
    double P[9] = { g[3],g[4],g[5], g[4],g[6],g[7], g[5],g[7],g[8] };
    if (l < TPB-1) {
      SE s = (b == 0) ? sufnext0 : se_load(&lds[(l+1)*SE_S]);  // LDS intact for b!=0
      sapply(s, m, P);
    }
    if (t == NTH-1) {                       // final merged index T_TOT-1
      int ik = (CHUNK-1)*NTH + t;
      int j = p.oix[ik];
      if (j >= 0) { p.out[j] = (float)(m[0] + mc); p.out[M_TEST + j] = (float)fmax(P[0], 0.0); }
    }
#pragma unroll
    for (int i = CHUNK-1; i >= 0; --i) {
      int k = CHUNK*t + i;
      if (k <= T_TOT-2) {
        SE e = build_selem(M, p.pk, p.mf, p.Pf, i, t);
        sapply(e, m, P);
        int ik = i*NTH + t;
        int j = p.oix[ik];
        if (j >= 0) { p.out[j] = (float)(m[0] + mc); p.out[M_TEST + j] = (float)fmax(P[0], 0.0); }
      }
    }
  }
}

extern "C" void kernel_launch(void* const* d_in, const int* in_sizes, int n_in,
                              void* d_out, int out_size, void* d_ws, size_t ws_size,
                              hipStream_t stream) {
  size_t off = 0;
  auto take = [&](size_t bytes) {
    char* ptr = (char*)d_ws + off;
    off += (bytes + 255) & ~(size_t)255;
    return (void*)ptr;
  };
  KP p;
  p.times = (const float*)d_in[0];
  p.tstar = (const float*)d_in[1];
  p.n1    = (const float*)d_in[2];
  p.n2    = (const float*)d_in[3];
  p.varp  = (const float*)d_in[4];
  p.ellp  = (const float*)d_in[5];
  p.mcp   = (const float*)d_in[6];
  p.out   = (float*)d_out;
  p.cnt   = (unsigned*)take(256);
  p.pk    = (float4*)take(sizeof(float4) * T_TOT);
  p.oix   = (int*)   take(sizeof(int)    * T_TOT);
  p.mf    = (double*)take(sizeof(double) * 3 * T_TOT);
  p.Pf    = (double*)take(sizeof(double) * 6 * T_TOT);
  p.blkAgg  = (double*)take(sizeof(double) * FE_S * NBLK);
  p.blkPref = (double*)take(sizeof(double) * FE_S * NBLK);
  p.blkAggS = (double*)take(sizeof(double) * 18 * NBLK);
  p.bExit   = (double*)take(sizeof(double) * 9  * NBLK);
  p.xT      = (double*)take(sizeof(double) * 9);
  (void)ws_size; (void)in_sizes; (void)n_in; (void)out_size;

  k_init<<<1, 64, 0, stream>>>(p.cnt);
  k_all <<<NBLK, TPB, 0, stream>>>(p);
}

// Round 6
// 164.846 us; speedup vs baseline: 1.6355x; 1.6355x over previous
//
#include <hip/hip_runtime.h>
#include <math.h>

#define DEV __device__ __forceinline__

constexpr int N_TRAIN = 131072;
constexpr int M_TEST  = 65536;
constexpr int T_TOT   = N_TRAIN + M_TEST;  // 196608
constexpr int CHUNK   = 4;
constexpr int NTH     = T_TOT / CHUNK;     // 49152 threads in heavy phases
constexpr int TPB     = 64;                // single-wave blocks
constexpr int NBLK    = NTH / TPB;         // 768 blocks
constexpr int MIDT    = 256;               // threads in mid-level scans (768 = 256*3)
constexpr int FE_S    = 33;                // FE LDS stride (doubles)
constexpr int SE_S    = 19;                // SE LDS stride (padded 18->19)

// CHUNK-transposed layout: for fixed inner step i, consecutive threads t are
// consecutive in memory -> coalesced.
DEV int IDX4(int k) { return (k & (CHUNK - 1)) * NTH + (k >> 2); }

// ---------------- 3x3 helpers (row-major double[9]) ----------------
DEV void mm(const double* X, const double* Y, double* Z) {
#pragma unroll
  for (int i = 0; i < 3; ++i)
#pragma unroll
    for (int j = 0; j < 3; ++j)
      Z[i*3+j] = X[i*3]*Y[j] + X[i*3+1]*Y[3+j] + X[i*3+2]*Y[6+j];
}
DEV void mmnt(const double* X, const double* Y, double* Z) { // X * Y^T
#pragma unroll
  for (int i = 0; i < 3; ++i)
#pragma unroll
    for (int j = 0; j < 3; ++j)
      Z[i*3+j] = X[i*3]*Y[j*3] + X[i*3+1]*Y[j*3+1] + X[i*3+2]*Y[j*3+2];
}
DEV void mtn(const double* X, const double* Y, double* Z) { // X^T * Y
#pragma unroll
  for (int i = 0; i < 3; ++i)
#pragma unroll
    for (int j = 0; j < 3; ++j)
      Z[i*3+j] = X[i]*Y[j] + X[3+i]*Y[3+j] + X[6+i]*Y[6+j];
}
DEV void mv(const double* X, const double* v, double* w) {
#pragma unroll
  for (int i = 0; i < 3; ++i) w[i] = X[i*3]*v[0] + X[i*3+1]*v[1] + X[i*3+2]*v[2];
}
DEV void mtv(const double* X, const double* v, double* w) {
#pragma unroll
  for (int i = 0; i < 3; ++i) w[i] = X[i]*v[0] + X[3+i]*v[1] + X[6+i]*v[2];
}
DEV void inv3(const double* m, double* o) {
  double c00 = m[4]*m[8] - m[5]*m[7];
  double c10 = m[5]*m[6] - m[3]*m[8];
  double c20 = m[3]*m[7] - m[4]*m[6];
  double det = m[0]*c00 + m[1]*c10 + m[2]*c20;
  double id = 1.0 / det;
  o[0] = c00*id; o[1] = (m[2]*m[7]-m[1]*m[8])*id; o[2] = (m[1]*m[5]-m[2]*m[4])*id;
  o[3] = c10*id; o[4] = (m[0]*m[8]-m[2]*m[6])*id; o[5] = (m[2]*m[3]-m[0]*m[5])*id;
  o[6] = c20*id; o[7] = (m[1]*m[6]-m[0]*m[7])*id; o[8] = (m[0]*m[4]-m[1]*m[3])*id;
}
DEV void symm(double* P) {
  double a = 0.5*(P[1]+P[3]), b = 0.5*(P[2]+P[6]), c = 0.5*(P[5]+P[7]);
  P[1]=P[3]=a; P[2]=P[6]=b; P[5]=P[7]=c;
}

// ---------------- model ----------------
struct Model { double lam, v, kap, l4; };
DEV Model make_model(const float* varp, const float* ellp) {
  Model M; M.v = (double)varp[0];
  double ell = (double)ellp[0];
  M.lam = sqrt(5.0) / ell;
  M.kap = M.lam * M.lam / 3.0;
  double l2 = M.lam * M.lam;
  M.l4 = l2 * l2;
  return M;
}
DEV void pinf(const Model& M, double* P) {
  double vk = M.v * M.kap;
  P[0]=M.v; P[1]=0;  P[2]=-vk;
  P[3]=0;   P[4]=vk; P[5]=0;
  P[6]=-vk; P[7]=0;  P[8]=M.v*M.l4;
}
// A = exp(dt*F) = e^{-lam dt}(I + dt*N + dt^2/2 N^2); Q = Pinf - A Pinf A^T
// exp via fp32 HW (lam*dt small here; rel err ~1e-7, below fp32-ref noise)
DEV void make_AQ(const Model& M, double dt, double* A, double* Q) {
  double lam = M.lam, l2 = lam*lam, l3 = l2*lam, l4 = M.l4;
  double e = (double)__expf((float)(-lam * dt));
  double h = 0.5 * dt * dt;
  A[0] = e*(1.0 + dt*lam + h*l2);
  A[1] = e*(dt + 2.0*h*lam);
  A[2] = e*h;
  A[3] = e*(-h*l3);
  A[4] = e*(1.0 + dt*lam - 2.0*h*l2);
  A[5] = e*(dt - h*lam);
  A[6] = e*(-dt*l3 + h*l4);
  A[7] = e*(-3.0*dt*l2 + 2.0*h*l3);
  A[8] = e*(1.0 - 2.0*dt*lam + h*l2);
  double vk = M.v * M.kap, vl4 = M.v * M.l4;
  double B[9];  // A * Pinf
#pragma unroll
  for (int i = 0; i < 3; ++i) {
    B[i*3+0] =  A[i*3+0]*M.v - A[i*3+2]*vk;
    B[i*3+1] =  A[i*3+1]*vk;
    B[i*3+2] = -A[i*3+0]*vk  + A[i*3+2]*vl4;
  }
  double Pi[9]; pinf(M, Pi);
#pragma unroll
  for (int i = 0; i < 3; ++i)
#pragma unroll
    for (int j = 0; j < 3; ++j)
      Q[i*3+j] = Pi[i*3+j] - (B[i*3]*A[j*3] + B[i*3+1]*A[j*3+1] + B[i*3+2]*A[j*3+2]);
}

// ---------------- filter scan element (Sarkka/Garcia-Fernandez) ----------------
struct FE { double A[9]; double b[3]; double C[9]; double h[3]; double J[9]; };

DEV FE fe_identity() {
  FE e;
#pragma unroll
  for (int i=0;i<9;++i){ e.A[i]=0.0; e.C[i]=0.0; e.J[i]=0.0; }
  e.A[0]=e.A[4]=e.A[8]=1.0;
  e.b[0]=e.b[1]=e.b[2]=0.0; e.h[0]=e.h[1]=e.h[2]=0.0;
  return e;
}
DEV void fe_store(const FE& e, double* g) {
#pragma unroll
  for (int i=0;i<9;++i) g[i]=e.A[i];
  g[9]=e.b[0]; g[10]=e.b[1]; g[11]=e.b[2];
#pragma unroll
  for (int i=0;i<9;++i) g[12+i]=e.C[i];
  g[21]=e.h[0]; g[22]=e.h[1]; g[23]=e.h[2];
#pragma unroll
  for (int i=0;i<9;++i) g[24+i]=e.J[i];
}
DEV FE fe_load(const double* g) {
  FE e;
#pragma unroll
  for (int i=0;i<9;++i) e.A[i]=g[i];
  e.b[0]=g[9]; e.b[1]=g[10]; e.b[2]=g[11];
#pragma unroll
  for (int i=0;i<9;++i) e.C[i]=g[12+i];
  e.h[0]=g[21]; e.h[1]=g[22]; e.h[2]=g[23];
#pragma unroll
  for (int i=0;i<9;++i) e.J[i]=g[24+i];
  return e;
}
DEV FE build_felem(const Model& M, double dt, float obsf, float rf, float Rf_, bool first) {
  FE E;
  double r = (double)rf, R = (double)Rf_;
  double g = (obsf > 0.5f) ? 1.0 : 0.0;
  if (first) {
#pragma unroll
    for (int i=0;i<9;++i){ E.A[i]=0.0; E.J[i]=0.0; }
    E.h[0]=E.h[1]=E.h[2]=0.0;
    double Pi[9]; pinf(M, Pi);
    double S = Pi[0] + R;
    double f = g / S;
    double K0=Pi[0]*f, K1=Pi[3]*f, K2=Pi[6]*f;
    E.b[0]=K0*r; E.b[1]=K1*r; E.b[2]=K2*r;
    E.C[0]=Pi[0]-S*K0*K0; E.C[1]=Pi[1]-S*K0*K1; E.C[2]=Pi[2]-S*K0*K2;
    E.C[3]=Pi[3]-S*K1*K0; E.C[4]=Pi[4]-S*K1*K1; E.C[5]=Pi[5]-S*K1*K2;
    E.C[6]=Pi[6]-S*K2*K0; E.C[7]=Pi[7]-S*K2*K1; E.C[8]=Pi[8]-S*K2*K2;
    return E;
  }
  double Am[9], Q[9]; make_AQ(M, dt, Am, Q);
  double S = Q[0] + R, iS = g / S;   // gated: obs=0 -> K=0, A=Am, C=Q, h=0, J=0
  double K0=Q[0]*iS, K1=Q[3]*iS, K2=Q[6]*iS;
#pragma unroll
  for (int j = 0; j < 3; ++j) {
    E.A[j]   = Am[j]   - K0*Am[j];
    E.A[3+j] = Am[3+j] - K1*Am[j];
    E.A[6+j] = Am[6+j] - K2*Am[j];
    E.C[j]   = Q[j]    - K0*Q[j];
    E.C[3+j] = Q[3+j]  - K1*Q[j];
    E.C[6+j] = Q[6+j]  - K2*Q[j];
  }
  E.b[0]=K0*r; E.b[1]=K1*r; E.b[2]=K2*r;
  double riS = r*iS;
  E.h[0]=Am[0]*riS; E.h[1]=Am[1]*riS; E.h[2]=Am[2]*riS;
#pragma unroll
  for (int i = 0; i < 3; ++i)
#pragma unroll
    for (int j = 0; j < 3; ++j)
      E.J[i*3+j] = Am[i]*Am[j]*iS;
  return E;
}
// compose: x earlier, y later
DEV FE fcompose(const FE& x, const FE& y) {
  const double *A1=x.A,*b1=x.b,*C1=x.C,*h1=x.h,*J1=x.J;
  const double *A2=y.A,*b2=y.b,*C2=y.C,*h2=y.h,*J2=y.J;
  FE o;
  double Mx[9]; mm(C1,J2,Mx); Mx[0]+=1.0; Mx[4]+=1.0; Mx[8]+=1.0;
  double Mi[9]; inv3(Mx,Mi);
  double T1[9]; mm(A2,Mi,T1);
  mm(T1,A1,o.A);
  double u[3]; mv(C1,h2,u); u[0]+=b1[0]; u[1]+=b1[1]; u[2]+=b1[2];
  mv(T1,u,o.b); o.b[0]+=b2[0]; o.b[1]+=b2[1]; o.b[2]+=b2[2];
  double t2[9]; mm(T1,C1,t2);
  mmnt(t2,A2,o.C);
#pragma unroll
  for (int i=0;i<9;++i) o.C[i]+=C2[i];
  double tmp[9]; mm(Mi,A1,tmp);
  double w[3]; mv(J2,b1,w);
  w[0]=h2[0]-w[0]; w[1]=h2[1]-w[1]; w[2]=h2[2]-w[2];
  mtv(tmp,w,o.h); o.h[0]+=h1[0]; o.h[1]+=h1[1]; o.h[2]+=h1[2];
  double V[9]; mm(J2,A1,V);
  mtn(tmp,V,o.J);
#pragma unroll
  for (int i=0;i<9;++i) o.J[i]+=J1[i];
  symm(o.C); symm(o.J);
  return o;
}
// plain Kalman step (replay phase)
DEV void fstep(const Model& M, double dt, float obsf, float rf, float Rf_,
               double* m, double* P) {
  double A[9], Q[9]; make_AQ(M, dt, A, Q);
  double mp[3]; mv(A, m, mp);
  double W[9]; mmnt(P, A, W);      // P A^T
  double Pp[9]; mm(A, W, Pp);
#pragma unroll
  for (int i=0;i<9;++i) Pp[i]+=Q[i];
  double S = Pp[0] + (double)Rf_;
  double f = (obsf > 0.5f) ? (1.0/S) : 0.0;
  double K0=Pp[0]*f, K1=Pp[3]*f, K2=Pp[6]*f;
  double v = (double)rf - mp[0];
  m[0]=mp[0]+K0*v; m[1]=mp[1]+K1*v; m[2]=mp[2]+K2*v;
  P[0]=Pp[0]-S*K0*K0; P[1]=Pp[1]-S*K0*K1; P[2]=Pp[2]-S*K0*K2;
  P[3]=Pp[3]-S*K1*K0; P[4]=Pp[4]-S*K1*K1; P[5]=Pp[5]-S*K1*K2;
  P[6]=Pp[6]-S*K2*K0; P[7]=Pp[7]-S*K2*K1; P[8]=Pp[8]-S*K2*K2;
  symm(P);
}

// ---------------- smoother affine map: x_k = G x_{k+1} + c ; P_k = G P G^T + U ----------------
struct SE { double G[9]; double c[3]; double U[9]; };

DEV SE se_identity() {
  SE s;
#pragma unroll
  for (int i=0;i<9;++i){ s.G[i]=0.0; s.U[i]=0.0; }
  s.G[0]=s.G[4]=s.G[8]=1.0;
  s.c[0]=s.c[1]=s.c[2]=0.0;
  return s;
}
DEV void se_store(const SE& s, double* g) {
#pragma unroll
  for (int i=0;i<9;++i) g[i]=s.G[i];
  g[9]=s.c[0]; g[10]=s.c[1]; g[11]=s.c[2];
  g[12]=s.U[0]; g[13]=s.U[1]; g[14]=s.U[2]; g[15]=s.U[4]; g[16]=s.U[5]; g[17]=s.U[8];
}
DEV SE se_load(const double* g) {
  SE s;
#pragma unroll
  for (int i=0;i<9;++i) s.G[i]=g[i];
  s.c[0]=g[9]; s.c[1]=g[10]; s.c[2]=g[11];
  s.U[0]=g[12]; s.U[1]=g[13]; s.U[2]=g[14];
  s.U[3]=g[13]; s.U[4]=g[15]; s.U[5]=g[16];
  s.U[6]=g[14]; s.U[7]=g[16]; s.U[8]=g[17];
  return s;
}
// x earlier in time (applied LAST, since smoother runs backward)
DEV SE scompose(const SE& x, const SE& y) {
  SE o;
  mm(x.G, y.G, o.G);
  double t[3]; mv(x.G, y.c, t);
  o.c[0]=t[0]+x.c[0]; o.c[1]=t[1]+x.c[1]; o.c[2]=t[2]+x.c[2];
  double T[9]; mm(x.G, y.U, T);
  mmnt(T, x.G, o.U);
#pragma unroll
  for (int i=0;i<9;++i) o.U[i]+=x.U[i];
  symm(o.U);
  return o;
}
DEV void sapply(const SE& s, double* m, double* P) {
  double t[3]; mv(s.G, m, t);
  double T[9]; mm(s.G, P, T);
  double Pn[9]; mmnt(T, s.G, Pn);
  m[0]=t[0]+s.c[0]; m[1]=t[1]+s.c[1]; m[2]=t[2]+s.c[2];
#pragma unroll
  for (int i=0;i<9;++i) P[i]=Pn[i]+s.U[i];
  symm(P);
}
// build smoother element for global index k = CHUNK*t + i  (valid for k <= T_TOT-2)
DEV SE build_selem(const Model& M, const float4* pk, const double* mf, const double* Pf,
                   int i, int t) {
  int ik  = i*NTH + t;
  int ik1 = (i < CHUNK-1) ? (ik + NTH) : (t + 1);
  double m[3] = { mf[ik], mf[T_TOT+ik], mf[2*T_TOT+ik] };
  double p00=Pf[ik], p01=Pf[T_TOT+ik], p02=Pf[2*T_TOT+ik],
         p11=Pf[3*T_TOT+ik], p12=Pf[4*T_TOT+ik], p22=Pf[5*T_TOT+ik];
  double P[9] = { p00,p01,p02, p01,p11,p12, p02,p12,p22 };
  double dt = (double)(pk[ik1].x - pk[ik].x);
  SE s;
  double A[9], Q[9]; make_AQ(M, dt, A, Q);
  double W[9]; mmnt(P, A, W);      // P A^T
  double Pp[9]; mm(A, W, Pp);
#pragma unroll
  for (int j=0;j<9;++j) Pp[j]+=Q[j];
  double Pi_[9]; inv3(Pp, Pi_);
  mm(W, Pi_, s.G);                 // G = P A^T Pp^-1
  double mp[3]; mv(A, m, mp);
  double gm[3]; mv(s.G, mp, gm);
  s.c[0]=m[0]-gm[0]; s.c[1]=m[1]-gm[1]; s.c[2]=m[2]-gm[2];
  double GW[9]; mmnt(s.G, W, GW);  // G Pp G^T
#pragma unroll
  for (int j=0;j<9;++j) s.U[j]=P[j]-GW[j];
  symm(s.U);
  return s;
}

// ================= kernels =================
// pk[IDX4(k)] = {time, residual, R, is_obs}
__global__ void k_merge(const float* __restrict__ times, const float* __restrict__ tstar,
                        const float* __restrict__ n1, const float* __restrict__ n2,
                        const float* __restrict__ mcp,
                        float4* pk, int* oix) {
  int g = blockIdx.x*blockDim.x + threadIdx.x;
  if (g >= T_TOT) return;
  float mc = mcp[0];
  if (g < N_TRAIN) {
    int i = g;
    float t = times[i];
    int lo = 0, hi = M_TEST;                 // count tstar strictly < t
    while (lo < hi) { int mid=(lo+hi)>>1; if (tstar[mid] < t) lo=mid+1; else hi=mid; }
    int p = i + lo, ip = IDX4(p);
    float s2 = n2[i];
    pk[ip] = make_float4(t, n1[i]/s2 - mc, 1.0f/s2, 1.0f);
    oix[ip] = -1;
  } else {
    int j = g - N_TRAIN;
    float t = tstar[j];
    int lo = 0, hi = N_TRAIN;                // count times <= t (stable: train first)
    while (lo < hi) { int mid=(lo+hi)>>1; if (times[mid] <= t) lo=mid+1; else hi=mid; }
    int p = j + lo, ip = IDX4(p);
    pk[ip] = make_float4(t, 0.f, 1.f, 0.f);
    oix[ip] = j;
  }
}

// F1: per-thread build+compose of 4 elements, then 64-wide single-wave scan.
// __launch_bounds__(64,2): 256-VGPR budget -> FE state stays in registers (no spill).
__global__ __launch_bounds__(TPB, 2) void k_f1(
    const float* varp, const float* ellp, const float4* __restrict__ pk,
    double* tIncl, double* blkAgg) {
  __shared__ double lds[TPB*FE_S];
  int l = threadIdx.x, b = blockIdx.x;
  int t = b*TPB + l;
  Model M = make_model(varp, ellp);
  FE run;
  float tprev = (t == 0) ? 0.0f : pk[(CHUNK-1)*NTH + (t-1)].x;
#pragma unroll
  for (int i = 0; i < CHUNK; ++i) {
    float4 q = pk[i*NTH + t];
    bool first = (t==0 && i==0);
    double dt = first ? 0.0 : (double)(q.x - tprev);
    tprev = q.x;
    FE e = build_felem(M, dt, q.w, q.y, q.z, first);
    run = (i == 0) ? e : fcompose(run, e);
  }
  fe_store(run, &lds[l*FE_S]);
  for (int d = 1; d < TPB; d <<= 1) {
    __syncthreads();
    FE oth; bool act = (l >= d);
    if (act) oth = fe_load(&lds[(l-d)*FE_S]);
    __syncthreads();
    if (act) { run = fcompose(oth, run); fe_store(run, &lds[l*FE_S]); }
  }
  fe_store(run, tIncl + t*33);
  if (l == TPB-1) fe_store(run, blkAgg + b*33);
}

// F2: one 256-thread block scans 768 block aggregates (3 per thread).
// __launch_bounds__(256,1): 512-VGPR budget, zero spill for the 3-element window.
__global__ __launch_bounds__(MIDT, 1) void k_f2(const double* __restrict__ blkAgg,
                                                double* blkPref) {
  __shared__ double lds[MIDT*FE_S];
  int j = threadIdx.x;
  FE run;
  { // keep only the 3-wide product live across the scan
    FE a0 = fe_load(blkAgg + (3*j+0)*33);
    FE a1 = fe_load(blkAgg + (3*j+1)*33);
    FE a2 = fe_load(blkAgg + (3*j+2)*33);
    run = fcompose(fcompose(a0, a1), a2);
  }
  fe_store(run, &lds[j*FE_S]);
  for (int d = 1; d < MIDT; d <<= 1) {
    __syncthreads();
    FE oth; bool act = (j >= d);
    if (act) oth = fe_load(&lds[(j-d)*FE_S]);
    __syncthreads();
    if (act) { run = fcompose(oth, run); fe_store(run, &lds[j*FE_S]); }
  }
  __syncthreads();
  FE X = (j == 0) ? fe_identity() : fe_load(&lds[(j-1)*FE_S]);
  fe_store(X, blkPref + (3*j+0)*33);
  FE a0 = fe_load(blkAgg + (3*j+0)*33);
  FE x1 = fcompose(X, a0);
  fe_store(x1, blkPref + (3*j+1)*33);
  FE a1 = fe_load(blkAgg + (3*j+1)*33);
  FE x2 = fcompose(x1, a1);
  fe_store(x2, blkPref + (3*j+2)*33);
}

// F3: entry state from (block prefix ∘ within-block exclusive prefix), replay 4 steps.
__global__ __launch_bounds__(TPB, 2) void k_f3(
    const float* varp, const float* ellp, const float4* __restrict__ pk,
    const double* __restrict__ tIncl, const double* __restrict__ blkPref,
    double* mf, double* Pf) {
  int l = threadIdx.x, b = blockIdx.x;
  int t = b*TPB + l;
  Model M = make_model(varp, ellp);
  double m[3], P[9];
  if (t == 0) {
    m[0]=m[1]=m[2]=0.0; pinf(M, P);
  } else {
    FE bp = fe_load(blkPref + b*33);
    FE ent = (l == 0) ? bp : fcompose(bp, fe_load(tIncl + (t-1)*33));
    m[0]=ent.b[0]; m[1]=ent.b[1]; m[2]=ent.b[2];
#pragma unroll
    for (int i=0;i<9;++i) P[i]=ent.C[i];
  }
  float tprev = (t == 0) ? 0.0f : pk[(CHUNK-1)*NTH + (t-1)].x;
#pragma unroll
  for (int i = 0; i < CHUNK; ++i) {
    int ik = i*NTH + t;
    float4 q = pk[ik];
    bool first = (t==0 && i==0);
    double dt = first ? 0.0 : (double)(q.x - tprev);
    tprev = q.x;
    fstep(M, dt, q.w, q.y, q.z, m, P);
    mf[ik]=m[0]; mf[T_TOT+ik]=m[1]; mf[2*T_TOT+ik]=m[2];
    Pf[ik]=P[0]; Pf[T_TOT+ik]=P[1]; Pf[2*T_TOT+ik]=P[2];
    Pf[3*T_TOT+ik]=P[4]; Pf[4*T_TOT+ik]=P[5]; Pf[5*T_TOT+ik]=P[8];
  }
}

// S1: per-thread backward compose of 4 smoother maps, then single-wave backward scan.
__global__ __launch_bounds__(TPB, 2) void k_s1(
    const float* varp, const float* ellp, const float4* __restrict__ pk,
    const double* __restrict__ mf, const double* __restrict__ Pf,
    double* tSuf, double* blkAggS) {
  __shared__ double lds[TPB*SE_S];
  int l = threadIdx.x, b = blockIdx.x;
  int t = b*TPB + l;
  Model M = make_model(varp, ellp);
  SE Macc = se_identity();
#pragma unroll
  for (int i = CHUNK-1; i >= 0; --i) {
    int k = t*CHUNK + i;
    if (k <= T_TOT-2) {
      SE e = build_selem(M, pk, mf, Pf, i, t);
      Macc = scompose(e, Macc);
    }
  }
  se_store(Macc, &lds[l*SE_S]);
  for (int d = 1; d < TPB; d <<= 1) {
    __syncthreads();
    SE oth; bool act = (l + d < TPB);
    if (act) oth = se_load(&lds[(l+d)*SE_S]);
    __syncthreads();
    if (act) { Macc = scompose(Macc, oth); se_store(Macc, &lds[l*SE_S]); }
  }
  se_store(Macc, tSuf + t*18);
  if (l == 0) se_store(Macc, blkAggS + b*18);
}

// S2: one 256-thread block backward-scans 768 aggregates (3/thread); emits per-block
// EXIT state (smoothed state at first index of block b+1).
__global__ __launch_bounds__(MIDT, 1) void k_s2(const double* __restrict__ blkAggS,
                                                const double* __restrict__ mf,
                                                const double* __restrict__ Pf,
                                                double* bExit) {
  __shared__ double lds[MIDT*SE_S];
  int j = threadIdx.x;
  SE run;
  {
    SE a0 = se_load(blkAggS + (3*j+0)*18);
    SE a1 = se_load(blkAggS + (3*j+1)*18);
    SE a2 = se_load(blkAggS + (3*j+2)*18);
    run = scompose(a0, scompose(a1, a2));
  }
  se_store(run, &lds[j*SE_S]);
  for (int d = 1; d < MIDT; d <<= 1) {
    __syncthreads();
    SE oth; bool act = (j + d < MIDT);
    if (act) oth = se_load(&lds[(j+d)*SE_S]);
    __syncthreads();
    if (act) { run = scompose(run, oth); se_store(run, &lds[j*SE_S]); }
  }
  __syncthreads();
  // final filtered (= smoothed) state
  int ikF = (CHUNK-1)*NTH + (NTH-1);
  double mT[3] = { mf[ikF], mf[T_TOT+ikF], mf[2*T_TOT+ikF] };
  double p00=Pf[ikF], p01=Pf[T_TOT+ikF], p02=Pf[2*T_TOT+ikF],
         p11=Pf[3*T_TOT+ikF], p12=Pf[4*T_TOT+ikF], p22=Pf[5*T_TOT+ikF];
  double PT[9] = { p00,p01,p02, p01,p11,p12, p02,p12,p22 };
  SE Sx = (j == MIDT-1) ? se_identity() : se_load(&lds[(j+1)*SE_S]);  // suffix of threads > j
  // exits for blocks 3j, 3j+1, 3j+2
  SE a1 = se_load(blkAggS + (3*j+1)*18);
  SE a2 = se_load(blkAggS + (3*j+2)*18);
  SE s2x = scompose(a2, Sx);
  SE s1x = scompose(a1, s2x);
  {
    double m[3]={mT[0],mT[1],mT[2]}, P[9];
#pragma unroll
    for (int i=0;i<9;++i) P[i]=PT[i];
    if (j < MIDT-1) sapply(Sx, m, P);   // j==MIDT-1: exit of last block is xT itself
    double* o = bExit + (3*j+2)*9;
    o[0]=m[0];o[1]=m[1];o[2]=m[2];o[3]=P[0];o[4]=P[1];o[5]=P[2];o[6]=P[4];o[7]=P[5];o[8]=P[8];
  }
  {
    double m[3]={mT[0],mT[1],mT[2]}, P[9];
#pragma unroll
    for (int i=0;i<9;++i) P[i]=PT[i];
    sapply(s2x, m, P);
    double* o = bExit + (3*j+1)*9;
    o[0]=m[0];o[1]=m[1];o[2]=m[2];o[3]=P[0];o[4]=P[1];o[5]=P[2];o[6]=P[4];o[7]=P[5];o[8]=P[8];
  }
  {
    double m[3]={mT[0],mT[1],mT[2]}, P[9];
#pragma unroll
    for (int i=0;i<9;++i) P[i]=PT[i];
    sapply(s1x, m, P);
    double* o = bExit + (3*j+0)*9;
    o[0]=m[0];o[1]=m[1];o[2]=m[2];o[3]=P[0];o[4]=P[1];o[5]=P[2];o[6]=P[4];o[7]=P[5];o[8]=P[8];
  }
}

// S3: thread exit state = tSuf[t+1] applied to block exit; replay 4 maps, emit outputs.
__global__ __launch_bounds__(TPB, 2) void k_s3(
    const float* varp, const float* ellp, const float* mcp,
    const float4* __restrict__ pk,
    const double* __restrict__ mf, const double* __restrict__ Pf,
    const double* __restrict__ tSuf, const double* __restrict__ bExit,
    const int* __restrict__ oix, float* out) {
  int l = threadIdx.x, b = blockIdx.x;
  int t = b*TPB + l;
  Model M = make_model(varp, ellp);
  double mc = (double)mcp[0];
  const double* g = bExit + b*9;
  double m[3] = { g[0], g[1], g[2] };
  double P[9] = { g[3],g[4],g[5], g[4],g[6],g[7], g[5],g[7],g[8] };
  if (l < TPB-1) {
    SE s = se_load(tSuf + (t+1)*18);
    sapply(s, m, P);
  }
  if (t == NTH-1) {                    // state at final merged index T_TOT-1
    int ik = (CHUNK-1)*NTH + t;
    int j = oix[ik];
    if (j >= 0) { out[j] = (float)(m[0] + mc); out[M_TEST + j] = (float)fmax(P[0], 0.0); }
  }
#pragma unroll
  for (int i = CHUNK-1; i >= 0; --i) {
    int k = t*CHUNK + i;
    if (k <= T_TOT-2) {
      SE e = build_selem(M, pk, mf, Pf, i, t);
      sapply(e, m, P);
      int ik = i*NTH + t;
      int j = oix[ik];
      if (j >= 0) { out[j] = (float)(m[0] + mc); out[M_TEST + j] = (float)fmax(P[0], 0.0); }
    }
  }
}

extern "C" void kernel_launch(void* const* d_in, const int* in_sizes, int n_in,
                              void* d_out, int out_size, void* d_ws, size_t ws_size,
                              hipStream_t stream) {
  const float* times = (const float*)d_in[0];
  const float* tstar = (const float*)d_in[1];
  const float* n1    = (const float*)d_in[2];
  const float* n2    = (const float*)d_in[3];
  const float* varp  = (const float*)d_in[4];
  const float* ellp  = (const float*)d_in[5];
  const float* mcp   = (const float*)d_in[6];
  float* out = (float*)d_out;

  size_t off = 0;
  auto take = [&](size_t bytes) {
    char* p = (char*)d_ws + off;
    off += (bytes + 255) & ~(size_t)255;
    return (void*)p;
  };
  float4* pk   = (float4*)take(sizeof(float4) * T_TOT);
  int*    oix  = (int*)   take(sizeof(int)    * T_TOT);
  double* mf   = (double*)take(sizeof(double) * 3 * T_TOT);
  double* Pf   = (double*)take(sizeof(double) * 6 * T_TOT);
  double* tIncl= (double*)take(sizeof(double) * 33 * NTH);
  double* blkAgg=(double*)take(sizeof(double) * 33 * NBLK);
  double* blkPref=(double*)take(sizeof(double)* 33 * NBLK);
  double* tSuf = (double*)take(sizeof(double) * 18 * NTH);
  double* blkAggS=(double*)take(sizeof(double)* 18 * NBLK);
  double* bExit= (double*)take(sizeof(double) * 9  * NBLK);
  (void)ws_size; (void)in_sizes; (void)n_in; (void)out_size;

  k_merge<<<(T_TOT+255)/256, 256, 0, stream>>>(times, tstar, n1, n2, mcp, pk, oix);
  k_f1   <<<NBLK, TPB, 0, stream>>>(varp, ellp, pk, tIncl, blkAgg);
  k_f2   <<<1, MIDT, 0, stream>>>(blkAgg, blkPref);
  k_f3   <<<NBLK, TPB, 0, stream>>>(varp, ellp, pk, tIncl, blkPref, mf, Pf);
  k_s1   <<<NBLK, TPB, 0, stream>>>(varp, ellp, pk, mf, Pf, tSuf, blkAggS);
  k_s2   <<<1, MIDT, 0, stream>>>(blkAggS, mf, Pf, bExit);
  k_s3   <<<NBLK, TPB, 0, stream>>>(varp, ellp, mcp, pk, mf, Pf, tSuf, bExit, oix, out);
}